// Round 1
// baseline (711.371 us; speedup 1.0000x reference)
//
#include <hip/hip_runtime.h>
#include <cstddef>

#define B_ 64
#define H_ 1024
#define L_ 400
#define V_ 50000
#define VP_ 50500   // V + OOV_PAD

typedef short short8 __attribute__((ext_vector_type(8)));
typedef float f32x4 __attribute__((ext_vector_type(4)));

static __device__ __forceinline__ short f2bf(float f) {
  unsigned u = __float_as_uint(f);
  u += 0x7fffu + ((u >> 16) & 1u);   // round-to-nearest-even
  return (short)(u >> 16);
}

static __device__ __forceinline__ short8 pack8(float4 a, float4 b) {
  short8 r;
  r[0] = f2bf(a.x); r[1] = f2bf(a.y); r[2] = f2bf(a.z); r[3] = f2bf(a.w);
  r[4] = f2bf(b.x); r[5] = f2bf(b.y); r[6] = f2bf(b.z); r[7] = f2bf(b.w);
  return r;
}

// ---------------- prep: gather embedding row, zero attn-context accumulator,
// ---------------- copy hidden -> output (module returns INPUT hidden)
__global__ void k_prep(const int* __restrict__ ids, const float* __restrict__ emb,
                       const float* __restrict__ hid, float* __restrict__ E,
                       float* __restrict__ A, float* __restrict__ hid_out) {
  int b = blockIdx.x;
  int t = threadIdx.x;                       // 256 threads * float4 = 1024
  int row = ids[b];
  float4 v = ((const float4*)(emb + (size_t)row * H_))[t];
  ((float4*)(E + (size_t)b * H_))[t] = v;
  ((float4*)(A + (size_t)b * H_))[t] = make_float4(0.f, 0.f, 0.f, 0.f);
  ((float4*)(hid_out + (size_t)b * H_))[t] = ((const float4*)(hid + (size_t)b * H_))[t];
}

// ---------------- generic MFMA GEMM: out[m=0..63][n] = sum_k X[m][k] * W[n][k] + bias[n]
// X supplied as one or two [64][1024] fp32 blocks (k<1024 -> X1, k>=1024 -> X2).
// Block = 256 threads = 4 waves; each wave owns a 16-wide n stripe; 4 m-tiles of 16.
__global__ __launch_bounds__(256) void k_gemm(
    const float* __restrict__ W, const float* __restrict__ bias,
    const float* __restrict__ X1, const float* __restrict__ X2,
    float* __restrict__ out, int N, int nkt, int ldo) {
  __shared__ short Xs[64 * 136];             // [64 m][128 k] bf16, row pad +8 shorts
  int tid = threadIdx.x;
  int wave = tid >> 6, lane = tid & 63;
  int q = lane >> 4, nl = lane & 15;
  int nbase = blockIdx.x * 64 + wave * 16 + nl;
  int nld = nbase < N ? nbase : (N - 1);     // clamp for safe loads
  int K = nkt * 128;
  const int ms = tid >> 2;                   // staging row (0..63)
  const int ks0 = (tid & 3) * 32;            // staging col (0..96)
  f32x4 acc0 = {0.f,0.f,0.f,0.f}, acc1 = {0.f,0.f,0.f,0.f};
  f32x4 acc2 = {0.f,0.f,0.f,0.f}, acc3 = {0.f,0.f,0.f,0.f};

  for (int kt = 0; kt < nkt; ++kt) {
    const float* Xsrc = (kt < 8) ? X1 : X2;
    int kofs = (kt & 7) * 128;
    __syncthreads();
    const float4* sp = (const float4*)(Xsrc + (size_t)ms * H_ + kofs + ks0);
    #pragma unroll
    for (int i = 0; i < 4; ++i) {
      float4 f0 = sp[2 * i], f1 = sp[2 * i + 1];
      *((short8*)&Xs[ms * 136 + ks0 + i * 8]) = pack8(f0, f1);
    }
    __syncthreads();
    const float* wr = W + (size_t)nld * K + kt * 128 + q * 8;
    #pragma unroll
    for (int ks = 0; ks < 4; ++ks) {
      float4 w0 = ((const float4*)(wr + ks * 32))[0];
      float4 w1 = ((const float4*)(wr + ks * 32))[1];
      short8 bf = pack8(w0, w1);
      int ao = ks * 32 + q * 8;
      short8 a0 = *((const short8*)&Xs[(0 * 16 + nl) * 136 + ao]);
      short8 a1 = *((const short8*)&Xs[(1 * 16 + nl) * 136 + ao]);
      short8 a2 = *((const short8*)&Xs[(2 * 16 + nl) * 136 + ao]);
      short8 a3 = *((const short8*)&Xs[(3 * 16 + nl) * 136 + ao]);
      acc0 = __builtin_amdgcn_mfma_f32_16x16x32_bf16(a0, bf, acc0, 0, 0, 0);
      acc1 = __builtin_amdgcn_mfma_f32_16x16x32_bf16(a1, bf, acc1, 0, 0, 0);
      acc2 = __builtin_amdgcn_mfma_f32_16x16x32_bf16(a2, bf, acc2, 0, 0, 0);
      acc3 = __builtin_amdgcn_mfma_f32_16x16x32_bf16(a3, bf, acc3, 0, 0, 0);
    }
  }
  if (nbase < N) {
    float bv = bias[nbase];
    #pragma unroll
    for (int r = 0; r < 4; ++r) {
      int mrow = q * 4 + r;                  // C/D: col=lane&15, row=quad*4+reg
      out[(size_t)(mrow)      * ldo + nbase] = acc0[r] + bv;
      out[(size_t)(mrow + 16) * ldo + nbase] = acc1[r] + bv;
      out[(size_t)(mrow + 32) * ldo + nbase] = acc2[r] + bv;
      out[(size_t)(mrow + 48) * ldo + nbase] = acc3[r] + bv;
    }
  }
}

// ---------------- attention softmax over L=400, one block per batch row
__global__ void k_softmax(const float* __restrict__ S, float* __restrict__ Wout) {
  __shared__ float red[512];
  int b = blockIdx.x, t = threadIdx.x;
  float v = (t < L_) ? S[b * L_ + t] : -1e30f;
  red[t] = v; __syncthreads();
  for (int s = 256; s > 0; s >>= 1) { if (t < s) red[t] = fmaxf(red[t], red[t + s]); __syncthreads(); }
  float m = red[0]; __syncthreads();
  float e = (t < L_) ? __expf(v - m) : 0.f;
  red[t] = e; __syncthreads();
  for (int s = 256; s > 0; s >>= 1) { if (t < s) red[t] += red[t + s]; __syncthreads(); }
  float z = red[0];
  if (t < L_) Wout[b * L_ + t] = e / z;
}

// ---------------- attn_applied[b][h] = sum_l w[b][l] * enc[l][b][h]
// grid (8 l-chunks of 50, 64 b), block 256 (float4 over H)
__global__ void k_attnapply(const float* __restrict__ enc, const float* __restrict__ aw,
                            float* __restrict__ A) {
  int lc = blockIdx.x, b = blockIdx.y, t = threadIdx.x;
  float4 acc = make_float4(0.f, 0.f, 0.f, 0.f);
  for (int l = lc * 50; l < lc * 50 + 50; ++l) {
    float w = aw[b * L_ + l];
    float4 e = ((const float4*)(enc + ((size_t)l * B_ + b) * H_))[t];
    acc.x += w * e.x; acc.y += w * e.y; acc.z += w * e.z; acc.w += w * e.w;
  }
  float* dst = A + (size_t)b * H_ + t * 4;
  atomicAdd(dst + 0, acc.x); atomicAdd(dst + 1, acc.y);
  atomicAdd(dst + 2, acc.z); atomicAdd(dst + 3, acc.w);
}

// ---------------- GRU elementwise (PyTorch r,z,n layout)
__global__ void k_gru(const float* __restrict__ gi, const float* __restrict__ gh,
                      const float* __restrict__ hid, float* __restrict__ hnew) {
  int idx = blockIdx.x * 256 + threadIdx.x;  // 65536
  int b = idx >> 10, h = idx & 1023;
  float ir = gi[b * 3072 + h], iz = gi[b * 3072 + 1024 + h], inn = gi[b * 3072 + 2048 + h];
  float hr = gh[b * 3072 + h], hz = gh[b * 3072 + 1024 + h], hn = gh[b * 3072 + 2048 + h];
  float r = 1.f / (1.f + __expf(-(ir + hr)));
  float z = 1.f / (1.f + __expf(-(iz + hz)));
  float n = tanhf(inn + r * hn);
  hnew[idx] = (1.f - z) * n + z * hid[idx];
}

// ---------------- p_gen = sigmoid([combined, h0] @ gen_W^T + gen_b), one block
__global__ void k_gen(const float* __restrict__ C, const float* __restrict__ hid,
                      const float* __restrict__ gW, const float* __restrict__ gb,
                      float* __restrict__ pg) {
  __shared__ float red[256];
  int t = threadIdx.x, b = t >> 2, p = t & 3;
  float acc = 0.f;
  for (int k = p * 512; k < p * 512 + 512; ++k) {
    float x = (k < 1024) ? C[b * H_ + k] : hid[b * H_ + k - 1024];
    acc += x * gW[k];
  }
  red[t] = acc; __syncthreads();
  if (p == 0) {
    float s = red[t] + red[t + 1] + red[t + 2] + red[t + 3] + gb[0];
    pg[b] = 1.f / (1.f + __expf(-s));
  }
}

// ---------------- per-row max + logsumexp over the 50000 raw logits in P
__global__ __launch_bounds__(1024) void k_rowred(const float* __restrict__ P,
                                                 float* __restrict__ logZ) {
  __shared__ float red[1024];
  int b = blockIdx.x, t = threadIdx.x;
  float m = -1e30f;
  for (int v = t; v < V_; v += 1024) m = fmaxf(m, P[(size_t)b * VP_ + v]);
  red[t] = m; __syncthreads();
  for (int s = 512; s > 0; s >>= 1) { if (t < s) red[t] = fmaxf(red[t], red[t + s]); __syncthreads(); }
  m = red[0]; __syncthreads();
  float sum = 0.f;
  for (int v = t; v < V_; v += 1024) sum += __expf(P[(size_t)b * VP_ + v] - m);
  red[t] = sum; __syncthreads();
  for (int s = 512; s > 0; s >>= 1) { if (t < s) red[t] += red[t + s]; __syncthreads(); }
  if (t == 0) logZ[b] = m + __logf(red[0]);
}

// ---------------- in-place: p_final[b][v] = p_gen*(logit - logZ) for v<V, 0 for pad
__global__ void k_final(float* __restrict__ P, const float* __restrict__ pg,
                        const float* __restrict__ logZ) {
  int b = blockIdx.y;
  int v0 = blockIdx.x * 1024 + threadIdx.x * 4;
  if (v0 >= VP_) return;
  float g = pg[b], lz = logZ[b];
  float4* p = (float4*)(P + (size_t)b * VP_ + v0);
  if (v0 < V_) {                              // 50000 % 4 == 0: no mixed quad
    float4 x = *p;
    x.x = g * (x.x - lz); x.y = g * (x.y - lz);
    x.z = g * (x.z - lz); x.w = g * (x.w - lz);
    *p = x;
  } else {
    *p = make_float4(0.f, 0.f, 0.f, 0.f);
  }
}

// ---------------- pointer-copy scatter: P[b][full_input[b][l]] += (1-p_gen)*w[b][l]
__global__ void k_scatter(float* __restrict__ P, const float* __restrict__ aw,
                          const int* __restrict__ fi, const float* __restrict__ pg) {
  int b = blockIdx.x, t = threadIdx.x;
  if (t >= L_) return;
  float g = 1.f - pg[b];
  int v = fi[b * L_ + t];
  atomicAdd(P + (size_t)b * VP_ + v, g * aw[b * L_ + t]);
}

extern "C" void kernel_launch(void* const* d_in, const int* in_sizes, int n_in,
                              void* d_out, int out_size, void* d_ws, size_t ws_size,
                              hipStream_t stream) {
  const int*   ids    = (const int*)d_in[0];
  const float* hid    = (const float*)d_in[1];
  const float* enc    = (const float*)d_in[2];
  const int*   fi     = (const int*)d_in[3];
  const float* emb    = (const float*)d_in[4];
  const float* attn_W = (const float*)d_in[5];
  const float* attn_b = (const float*)d_in[6];
  const float* comb_W = (const float*)d_in[7];
  const float* comb_b = (const float*)d_in[8];
  const float* W_ih   = (const float*)d_in[9];
  const float* W_hh   = (const float*)d_in[10];
  const float* b_ih   = (const float*)d_in[11];
  const float* b_hh   = (const float*)d_in[12];
  const float* out_W  = (const float*)d_in[13];
  const float* out_b  = (const float*)d_in[14];
  const float* gen_W  = (const float*)d_in[15];
  const float* gen_b  = (const float*)d_in[16];

  float* outp    = (float*)d_out;
  float* P       = outp;                              // [64][50500]
  float* hid_out = outp + (size_t)B_ * VP_;           // [1][64][1024]
  float* aw_out  = hid_out + B_ * H_;                 // [64][400]

  float* ws = (float*)d_ws;
  float* E  = ws;                     // [64][1024] embedded
  float* A  = E + B_ * H_;            // [64][1024] attn_applied (atomics)
  float* C  = A + B_ * H_;            // [64][1024] combined
  float* HN = C + B_ * H_;            // [64][1024] h_new
  float* S  = HN + B_ * H_;           // [64][400] attn logits
  float* GI = S + B_ * L_;            // [64][3072]
  float* GH = GI + B_ * 3 * H_;       // [64][3072]
  float* PG = GH + B_ * 3 * H_;       // [64]
  float* LZ = PG + B_;                // [64]

  k_prep<<<64, 256, 0, stream>>>(ids, emb, hid, E, A, hid_out);
  k_gemm<<<7,   256, 0, stream>>>(attn_W, attn_b, E, hid, S, L_, 16, L_);
  k_softmax<<<64, 512, 0, stream>>>(S, aw_out);
  k_attnapply<<<dim3(8, 64), 256, 0, stream>>>(enc, aw_out, A);
  k_gemm<<<16,  256, 0, stream>>>(comb_W, comb_b, E, A, C, H_, 16, H_);
  k_gemm<<<48,  256, 0, stream>>>(W_ih, b_ih, C, nullptr, GI, 3 * H_, 8, 3 * H_);
  k_gemm<<<48,  256, 0, stream>>>(W_hh, b_hh, hid, nullptr, GH, 3 * H_, 8, 3 * H_);
  k_gru<<<256,  256, 0, stream>>>(GI, GH, hid, HN);
  k_gen<<<1,    256, 0, stream>>>(C, hid, gen_W, gen_b, PG);
  k_gemm<<<782, 256, 0, stream>>>(out_W, out_b, HN, nullptr, P, V_, 8, VP_);
  k_rowred<<<64, 1024, 0, stream>>>(P, LZ);
  k_final<<<dim3(50, 64), 256, 0, stream>>>(P, PG, LZ);
  k_scatter<<<64, 512, 0, stream>>>(P, aw_out, fi, PG);
}

// Round 2
// 609.888 us; speedup vs baseline: 1.1664x; 1.1664x over previous
//
#include <hip/hip_runtime.h>
#include <cstddef>

#define B_ 64
#define H_ 1024
#define L_ 400
#define V_ 50000
#define VP_ 50500   // V + OOV_PAD

typedef short short8 __attribute__((ext_vector_type(8)));
typedef float f32x4 __attribute__((ext_vector_type(4)));

static __device__ __forceinline__ short f2bf(float f) {
  unsigned u = __float_as_uint(f);
  u += 0x7fffu + ((u >> 16) & 1u);   // round-to-nearest-even
  return (short)(u >> 16);
}

static __device__ __forceinline__ short8 pack8(float4 a, float4 b) {
  short8 r;
  r[0] = f2bf(a.x); r[1] = f2bf(a.y); r[2] = f2bf(a.z); r[3] = f2bf(a.w);
  r[4] = f2bf(b.x); r[5] = f2bf(b.y); r[6] = f2bf(b.z); r[7] = f2bf(b.w);
  return r;
}

// ---------------- prep: gather embedding row, zero attn-context accumulator,
// ---------------- copy hidden -> output (module returns INPUT hidden)
__global__ void k_prep(const int* __restrict__ ids, const float* __restrict__ emb,
                       const float* __restrict__ hid, float* __restrict__ E,
                       float* __restrict__ A, float* __restrict__ hid_out) {
  int b = blockIdx.x;
  int t = threadIdx.x;                       // 256 threads * float4 = 1024
  int row = ids[b];
  float4 v = ((const float4*)(emb + (size_t)row * H_))[t];
  ((float4*)(E + (size_t)b * H_))[t] = v;
  ((float4*)(A + (size_t)b * H_))[t] = make_float4(0.f, 0.f, 0.f, 0.f);
  ((float4*)(hid_out + (size_t)b * H_))[t] = ((const float4*)(hid + (size_t)b * H_))[t];
}

// ---------------- small GEMM: out[m=0..63][n] = sum_k X[m][k]*W[n][k] + bias[n]
// Block = 16 n-columns, 4 waves K-split 4-way, LDS cross-wave reduce.
// X given as fp32: k<1024 -> Xa, k>=1024 -> Xb (concat). Two param sets via blockIdx.y.
__global__ __launch_bounds__(256) void k_gemm_small(
    const float* __restrict__ W0, const float* __restrict__ bias0,
    const float* __restrict__ Xa0, const float* __restrict__ Xb0,
    float* __restrict__ out0, int N0, int K0, int ldo0,
    const float* __restrict__ W1, const float* __restrict__ bias1,
    const float* __restrict__ Xa1, const float* __restrict__ Xb1,
    float* __restrict__ out1, int N1, int K1, int ldo1) {
  const float* W  = blockIdx.y ? W1  : W0;
  const float* bias = blockIdx.y ? bias1 : bias0;
  const float* Xa = blockIdx.y ? Xa1 : Xa0;
  const float* Xb = blockIdx.y ? Xb1 : Xb0;
  float* out = blockIdx.y ? out1 : out0;
  int N = blockIdx.y ? N1 : N0;
  int K = blockIdx.y ? K1 : K0;
  int ldo = blockIdx.y ? ldo1 : ldo0;

  int tid = threadIdx.x, wave = tid >> 6, lane = tid & 63;
  int q = lane >> 4, nl = lane & 15;
  int n = blockIdx.x * 16 + nl;
  int nld = n < N ? n : (N - 1);
  int kpw = K >> 2;                          // K per wave
  int kbeg = wave * kpw;
  const float* wr = W + (size_t)nld * K;

  f32x4 acc[4];
  #pragma unroll
  for (int i = 0; i < 4; ++i) acc[i] = (f32x4){0.f, 0.f, 0.f, 0.f};

  for (int k0 = kbeg; k0 < kbeg + kpw; k0 += 32) {
    int kk = k0 + q * 8;                     // halves never straddle (32 | 1024)
    float4 w0 = *(const float4*)(wr + kk);
    float4 w1 = *(const float4*)(wr + kk + 4);
    short8 bf = pack8(w0, w1);
    const float* Xsel = (kk < 1024) ? Xa : Xb;
    int kx = kk & 1023;
    #pragma unroll
    for (int mt = 0; mt < 4; ++mt) {
      const float* xp = Xsel + (size_t)(mt * 16 + nl) * H_ + kx;
      float4 x0 = *(const float4*)xp;
      float4 x1 = *(const float4*)(xp + 4);
      short8 af = pack8(x0, x1);
      acc[mt] = __builtin_amdgcn_mfma_f32_16x16x32_bf16(af, bf, acc[mt], 0, 0, 0);
    }
  }

  __shared__ float red[4][64][16];           // [wave][m][nl] = 16 KB
  #pragma unroll
  for (int mt = 0; mt < 4; ++mt)
    #pragma unroll
    for (int r = 0; r < 4; ++r)
      red[wave][mt * 16 + q * 4 + r][nl] = acc[mt][r];
  __syncthreads();
  for (int i = tid; i < 1024; i += 256) {
    int m = i >> 4, c = i & 15;
    int nn = blockIdx.x * 16 + c;
    if (nn < N) {
      float s = red[0][m][c] + red[1][m][c] + red[2][m][c] + red[3][m][c] + bias[nn];
      out[(size_t)m * ldo + nn] = s;
    }
  }
}

// ---------------- fused attention softmax + apply.
// grid (16 l-chunks of 25, 64 b). Each block recomputes the 400-wide softmax
// (cheap) in LDS, applies its l-chunk, atomically accumulates into A.
__global__ __launch_bounds__(256) void k_attnsm(
    const float* __restrict__ S, const float* __restrict__ enc,
    float* __restrict__ aw_out, float* __restrict__ A) {
  __shared__ float w[L_];
  __shared__ float red[256];
  int lc = blockIdx.x, b = blockIdx.y, t = threadIdx.x;
  float a0 = S[b * L_ + t];                          // t < 256 < 400
  float a1 = (t < L_ - 256) ? S[b * L_ + 256 + t] : -1e30f;
  float m = fmaxf(a0, a1);
  red[t] = m; __syncthreads();
  for (int s = 128; s > 0; s >>= 1) { if (t < s) red[t] = fmaxf(red[t], red[t + s]); __syncthreads(); }
  m = red[0]; __syncthreads();
  float e0 = __expf(a0 - m);
  float e1 = (t < L_ - 256) ? __expf(a1 - m) : 0.f;
  red[t] = e0 + e1; __syncthreads();
  for (int s = 128; s > 0; s >>= 1) { if (t < s) red[t] += red[t + s]; __syncthreads(); }
  float z = red[0];
  w[t] = e0 / z;
  if (t < L_ - 256) w[256 + t] = e1 / z;
  __syncthreads();
  if (lc == 0) {
    aw_out[b * L_ + t] = w[t];
    if (t < L_ - 256) aw_out[b * L_ + 256 + t] = w[256 + t];
  }
  float4 acc = make_float4(0.f, 0.f, 0.f, 0.f);
  for (int l = lc * 25; l < lc * 25 + 25; ++l) {
    float wg = w[l];
    float4 e = ((const float4*)(enc + ((size_t)l * B_ + b) * H_))[t];
    acc.x += wg * e.x; acc.y += wg * e.y; acc.z += wg * e.z; acc.w += wg * e.w;
  }
  float* dst = A + (size_t)b * H_ + t * 4;
  atomicAdd(dst + 0, acc.x); atomicAdd(dst + 1, acc.y);
  atomicAdd(dst + 2, acc.z); atomicAdd(dst + 3, acc.w);
}

// ---------------- GRU elementwise (writes h_new as bf16) + p_gen blocks
__global__ __launch_bounds__(256) void k_gru_gen(
    const float* __restrict__ gi, const float* __restrict__ gh,
    const float* __restrict__ hid, short* __restrict__ HNb,
    const float* __restrict__ C, const float* __restrict__ gW,
    const float* __restrict__ gb, float* __restrict__ PG) {
  __shared__ float red[256];
  int blk = blockIdx.x, t = threadIdx.x;
  if (blk < 256) {
    int idx = blk * 256 + t;                 // 65536
    int b = idx >> 10, h = idx & 1023;
    float ir = gi[b * 3072 + h], iz = gi[b * 3072 + 1024 + h], inn = gi[b * 3072 + 2048 + h];
    float hr = gh[b * 3072 + h], hz = gh[b * 3072 + 1024 + h], hn = gh[b * 3072 + 2048 + h];
    float r = 1.f / (1.f + __expf(-(ir + hr)));
    float z = 1.f / (1.f + __expf(-(iz + hz)));
    float n = tanhf(inn + r * hn);
    HNb[idx] = f2bf((1.f - z) * n + z * hid[idx]);
  } else {
    int b = blk - 256;
    float acc = 0.f;
    for (int k = t; k < 2 * H_; k += 256) {
      float x = (k < H_) ? C[b * H_ + k] : hid[b * H_ + k - H_];
      acc += x * gW[k];
    }
    red[t] = acc; __syncthreads();
    for (int s = 128; s > 0; s >>= 1) { if (t < s) red[t] += red[t + s]; __syncthreads(); }
    if (t == 0) PG[b] = 1.f / (1.f + __expf(-(red[0] + gb[0])));
  }
}

// ---------------- vocab GEMM: P[m][n] = sum_k HNb[m][k]*out_W[n][k] + out_b[n]
// No LDS, no barriers: A-fragments straight from L2-resident bf16 HNb,
// W streamed from HBM with in-register bf16 pack. 4 waves * 16 n = 64 n/block.
__global__ __launch_bounds__(256) void k_gemm_vocab(
    const short* __restrict__ Xb, const float* __restrict__ W,
    const float* __restrict__ bias, float* __restrict__ P) {
  int tid = threadIdx.x, wave = tid >> 6, lane = tid & 63;
  int q = lane >> 4, nl = lane & 15;
  int n = blockIdx.x * 64 + wave * 16 + nl;
  int nld = n < V_ ? n : (V_ - 1);
  const float* wr = W + (size_t)nld * H_;
  f32x4 acc[4];
  #pragma unroll
  for (int i = 0; i < 4; ++i) acc[i] = (f32x4){0.f, 0.f, 0.f, 0.f};

  for (int k0 = 0; k0 < H_; k0 += 32) {
    int kk = k0 + q * 8;
    float4 w0 = *(const float4*)(wr + kk);
    float4 w1 = *(const float4*)(wr + kk + 4);
    short8 bf = pack8(w0, w1);
    #pragma unroll
    for (int mt = 0; mt < 4; ++mt) {
      short8 af = *(const short8*)(Xb + (size_t)(mt * 16 + nl) * H_ + kk);
      acc[mt] = __builtin_amdgcn_mfma_f32_16x16x32_bf16(af, bf, acc[mt], 0, 0, 0);
    }
  }
  if (n < V_) {
    float bv = bias[n];
    #pragma unroll
    for (int mt = 0; mt < 4; ++mt)
      #pragma unroll
      for (int r = 0; r < 4; ++r)
        P[(size_t)(mt * 16 + q * 4 + r) * VP_ + n] = acc[mt][r] + bv;
  }
}

// ---------------- per-row-chunk max + sumexp (4 chunks per row, 256 blocks)
__global__ __launch_bounds__(256) void k_rowred2(const float* __restrict__ P,
                                                 float* __restrict__ MX,
                                                 float* __restrict__ SE) {
  __shared__ float red[256];
  int b = blockIdx.x >> 2, c = blockIdx.x & 3;
  int t = threadIdx.x;
  int v0 = c * 12500, v1 = v0 + 12500;
  float m = -1e30f;
  for (int v = v0 + t; v < v1; v += 256) m = fmaxf(m, P[(size_t)b * VP_ + v]);
  red[t] = m; __syncthreads();
  for (int s = 128; s > 0; s >>= 1) { if (t < s) red[t] = fmaxf(red[t], red[t + s]); __syncthreads(); }
  m = red[0]; __syncthreads();
  float sum = 0.f;
  for (int v = v0 + t; v < v1; v += 256) sum += __expf(P[(size_t)b * VP_ + v] - m);
  red[t] = sum; __syncthreads();
  for (int s = 128; s > 0; s >>= 1) { if (t < s) red[t] += red[t + s]; __syncthreads(); }
  if (t == 0) { MX[blockIdx.x] = m; SE[blockIdx.x] = red[0]; }
}

// ---------------- in-place: p_final[b][v] = p_gen*(logit - logZ) for v<V, 0 pad
__global__ void k_final(float* __restrict__ P, const float* __restrict__ pg,
                        const float* __restrict__ MX, const float* __restrict__ SE) {
  int b = blockIdx.y;
  float m0 = MX[b * 4], m1 = MX[b * 4 + 1], m2 = MX[b * 4 + 2], m3 = MX[b * 4 + 3];
  float M = fmaxf(fmaxf(m0, m1), fmaxf(m2, m3));
  float Z = SE[b * 4] * __expf(m0 - M) + SE[b * 4 + 1] * __expf(m1 - M)
          + SE[b * 4 + 2] * __expf(m2 - M) + SE[b * 4 + 3] * __expf(m3 - M);
  float lz = M + __logf(Z);
  float g = pg[b];
  int v0 = blockIdx.x * 1024 + threadIdx.x * 4;
  if (v0 >= VP_) return;
  float4* p = (float4*)(P + (size_t)b * VP_ + v0);
  if (v0 < V_) {                              // 50000 % 4 == 0: no mixed quad
    float4 x = *p;
    x.x = g * (x.x - lz); x.y = g * (x.y - lz);
    x.z = g * (x.z - lz); x.w = g * (x.w - lz);
    *p = x;
  } else {
    *p = make_float4(0.f, 0.f, 0.f, 0.f);
  }
}

// ---------------- pointer-copy scatter: P[b][full_input[b][l]] += (1-p_gen)*w[b][l]
__global__ void k_scatter(float* __restrict__ P, const float* __restrict__ aw,
                          const int* __restrict__ fi, const float* __restrict__ pg) {
  int b = blockIdx.x, t = threadIdx.x;
  if (t >= L_) return;
  float g = 1.f - pg[b];
  int v = fi[b * L_ + t];
  atomicAdd(P + (size_t)b * VP_ + v, g * aw[b * L_ + t]);
}

extern "C" void kernel_launch(void* const* d_in, const int* in_sizes, int n_in,
                              void* d_out, int out_size, void* d_ws, size_t ws_size,
                              hipStream_t stream) {
  const int*   ids    = (const int*)d_in[0];
  const float* hid    = (const float*)d_in[1];
  const float* enc    = (const float*)d_in[2];
  const int*   fi     = (const int*)d_in[3];
  const float* emb    = (const float*)d_in[4];
  const float* attn_W = (const float*)d_in[5];
  const float* attn_b = (const float*)d_in[6];
  const float* comb_W = (const float*)d_in[7];
  const float* comb_b = (const float*)d_in[8];
  const float* W_ih   = (const float*)d_in[9];
  const float* W_hh   = (const float*)d_in[10];
  const float* b_ih   = (const float*)d_in[11];
  const float* b_hh   = (const float*)d_in[12];
  const float* out_W  = (const float*)d_in[13];
  const float* out_b  = (const float*)d_in[14];
  const float* gen_W  = (const float*)d_in[15];
  const float* gen_b  = (const float*)d_in[16];

  float* outp    = (float*)d_out;
  float* P       = outp;                              // [64][50500]
  float* hid_out = outp + (size_t)B_ * VP_;           // [1][64][1024]
  float* aw_out  = hid_out + B_ * H_;                 // [64][400]

  float* ws = (float*)d_ws;
  float* E   = ws;                      // [64][1024]
  float* A   = E + B_ * H_;             // [64][1024] attn_applied (atomics)
  float* C   = A + B_ * H_;             // [64][1024] combined
  float* S   = C + B_ * H_;             // [64][400] attn logits (bias included)
  float* GI  = S + B_ * L_;             // [64][3072]
  float* GH  = GI + B_ * 3 * H_;        // [64][3072]
  float* PG  = GH + B_ * 3 * H_;        // [64]
  float* MX  = PG + B_;                 // [256]
  float* SE  = MX + 256;                // [256]
  short* HNb = (short*)(SE + 256);      // [64][1024] bf16 h_new

  k_prep<<<64, 256, 0, stream>>>(ids, emb, hid, E, A, hid_out);
  k_gemm_small<<<dim3(25, 1), 256, 0, stream>>>(
      attn_W, attn_b, E, hid, S, L_, 2 * H_, L_,
      attn_W, attn_b, E, hid, S, L_, 2 * H_, L_);
  k_attnsm<<<dim3(16, 64), 256, 0, stream>>>(S, enc, aw_out, A);
  k_gemm_small<<<dim3(64, 1), 256, 0, stream>>>(
      comb_W, comb_b, E, A, C, H_, 2 * H_, H_,
      comb_W, comb_b, E, A, C, H_, 2 * H_, H_);
  k_gemm_small<<<dim3(192, 2), 256, 0, stream>>>(
      W_ih, b_ih, C, C, GI, 3 * H_, H_, 3 * H_,
      W_hh, b_hh, hid, hid, GH, 3 * H_, H_, 3 * H_);
  k_gru_gen<<<320, 256, 0, stream>>>(GI, GH, hid, HNb, C, gen_W, gen_b, PG);
  k_gemm_vocab<<<782, 256, 0, stream>>>(HNb, out_W, out_b, P);
  k_rowred2<<<256, 256, 0, stream>>>(P, MX, SE);
  k_final<<<dim3(50, 64), 256, 0, stream>>>(P, PG, MX, SE);
  k_scatter<<<64, 512, 0, stream>>>(P, aw_out, fi, PG);
}